// Round 1
// baseline (118.108 us; speedup 1.0000x reference)
//
#include <hip/hip_runtime.h>

#define HH 1024
#define WW 1024
#define NA 64

// Kernel 1: compute influence map + blend, write upd, accumulate
// sum(field^2) and sum(upd^2) into ws[0], ws[1] (doubles).
__global__ __launch_bounds__(256) void frp_fused(
    const float* __restrict__ field,
    const float* __restrict__ signal,
    const int*   __restrict__ apos,       // [NA][2]
    const float* __restrict__ astr,       // [NA]
    const float* __restrict__ p_is,       // influence_strength
    const float* __restrict__ p_gr,       // global_ratio
    const float* __restrict__ p_lr,       // local_ratio
    float* __restrict__ out,
    double* __restrict__ ws)
{
    __shared__ int   s_pi[NA];
    __shared__ int   s_pj[NA];
    __shared__ int   s_rad[NA];
    __shared__ float s_coef[NA];
    __shared__ float s_inv[NA];
    __shared__ double s_part[2][4];

    const float lr = *p_lr;
    const float gr = *p_gr;
    const float is = *p_is;

    int t = threadIdx.x;
    if (t < NA) {
        float s = astr[t];
        s_pi[t]   = apos[2 * t + 0];
        s_pj[t]   = apos[2 * t + 1];
        s_rad[t]  = (int)floorf(5.0f * s);
        s_coef[t] = lr * s;
        s_inv[t]  = -0.125f / (s * s);   // = -0.5 / (4 s^2)
    }
    __syncthreads();

    int p = blockIdx.x * 256 + t;        // 4096 blocks cover 1M pixels
    int i = p >> 10;                     // row (uniform within block)
    int j = p & 1023;                    // col

    float contrib = 0.0f;
#pragma unroll 4
    for (int a = 0; a < NA; ++a) {
        int di = i - s_pi[a];
        int r  = s_rad[a];
        if (di >= -r && di <= r) {       // wave-uniform: i same for all lanes
            int dj = j - s_pj[a];
            if (dj >= -r && dj <= r) {
                float d2 = (float)(di * di + dj * dj);
                contrib += s_coef[a] * __expf(s_inv[a] * d2) ;
            }
        }
    }

    // sigmoid(gr + contrib), clipped to [0,1] (sigmoid already in (0,1))
    float x  = gr + contrib;
    float im = 1.0f / (1.0f + expf(-x));
    im = fminf(fmaxf(im, 0.0f), 1.0f);
    float aw = im * is;

    float f  = field[p];
    float sg = signal[p];
    float u  = f * (1.0f - aw) + sg * aw;
    out[p] = u;

    // reduction: sum f^2 and u^2
    double sf = (double)f * (double)f;
    double su = (double)u * (double)u;
#pragma unroll
    for (int off = 32; off > 0; off >>= 1) {
        sf += __shfl_down(sf, off, 64);
        su += __shfl_down(su, off, 64);
    }
    int wave = t >> 6;
    int lane = t & 63;
    if (lane == 0) {
        s_part[0][wave] = sf;
        s_part[1][wave] = su;
    }
    __syncthreads();
    if (t == 0) {
        double tf = s_part[0][0] + s_part[0][1] + s_part[0][2] + s_part[0][3];
        double tu = s_part[1][0] + s_part[1][1] + s_part[1][2] + s_part[1][3];
        atomicAdd(&ws[0], tf);
        atomicAdd(&ws[1], tu);
    }
}

// Kernel 2: scale out by norm(field)/norm(upd)
__global__ __launch_bounds__(256) void frp_scale(
    float4* __restrict__ out, const double* __restrict__ ws)
{
    double tf = ws[0];
    double tu = ws[1];
    float scale = (tu > 0.0) ? (float)sqrt(tf / tu) : 1.0f;
    int p = blockIdx.x * 256 + threadIdx.x;   // 262144 float4s
    float4 v = out[p];
    v.x *= scale; v.y *= scale; v.z *= scale; v.w *= scale;
    out[p] = v;
}

extern "C" void kernel_launch(void* const* d_in, const int* in_sizes, int n_in,
                              void* d_out, int out_size, void* d_ws, size_t ws_size,
                              hipStream_t stream) {
    const float* field  = (const float*)d_in[0];
    const float* signal = (const float*)d_in[1];
    const int*   apos   = (const int*)d_in[2];
    const float* astr   = (const float*)d_in[3];
    const float* p_is   = (const float*)d_in[4];
    const float* p_gr   = (const float*)d_in[5];
    const float* p_lr   = (const float*)d_in[6];

    hipMemsetAsync(d_ws, 0, 2 * sizeof(double), stream);

    frp_fused<<<(HH * WW) / 256, 256, 0, stream>>>(
        field, signal, apos, astr, p_is, p_gr, p_lr,
        (float*)d_out, (double*)d_ws);

    frp_scale<<<(HH * WW) / (256 * 4), 256, 0, stream>>>(
        (float4*)d_out, (const double*)d_ws);
}

// Round 2
// 17.529 us; speedup vs baseline: 6.7378x; 6.7378x over previous
//
#include <hip/hip_runtime.h>

#define HH 1024
#define WW 1024
#define NA 64
#define NBLK 1024   // kernel-1 blocks: one row per block

// ws layout: [0..NBLK) double sum(field^2) partials,
//            [NBLK..2*NBLK) double sum(upd^2) partials,
//            then 1 float scale.

// Kernel 1: influence map + blend, 4 px/thread, per-block partial sums.
__global__ __launch_bounds__(256) void frp_fused(
    const float4* __restrict__ field,
    const float4* __restrict__ signal,
    const int*   __restrict__ apos,       // [NA][2]
    const float* __restrict__ astr,       // [NA]
    const float* __restrict__ p_is,
    const float* __restrict__ p_gr,
    const float* __restrict__ p_lr,
    float4* __restrict__ out,
    double* __restrict__ pf,
    double* __restrict__ pu)
{
    __shared__ int   s_pi[NA];
    __shared__ int   s_pj[NA];
    __shared__ int   s_rad[NA];
    __shared__ float s_coef[NA];
    __shared__ float s_inv[NA];
    __shared__ float s_part[2][4];

    const float lr = *p_lr;
    const float gr = *p_gr;
    const float is = *p_is;

    int t = threadIdx.x;
    if (t < NA) {
        float s = astr[t];
        s_pi[t]   = apos[2 * t + 0];
        s_pj[t]   = apos[2 * t + 1];
        s_rad[t]  = (int)floorf(5.0f * s);
        s_coef[t] = lr * s;
        s_inv[t]  = -0.125f / (s * s);   // = -0.5 / (4 s^2)
    }
    __syncthreads();

    const int row  = blockIdx.x;         // one row per block
    const int col0 = t << 2;             // 4 consecutive columns per thread

    float c0 = 0.f, c1 = 0.f, c2 = 0.f, c3 = 0.f;
    for (int a = 0; a < NA; ++a) {
        int r  = s_rad[a];
        int di = row - s_pi[a];
        if (di >= -r && di <= r) {       // block-uniform: skips ~94% of attractors
            int di2  = di * di;
            int dj   = col0 - s_pj[a];
            float cf = s_coef[a];
            float iv = s_inv[a];
            if (dj     >= -r && dj     <= r) c0 += cf * __expf(iv * (float)(di2 + dj * dj));
            int d1 = dj + 1;
            if (d1     >= -r && d1     <= r) c1 += cf * __expf(iv * (float)(di2 + d1 * d1));
            int d2 = dj + 2;
            if (d2     >= -r && d2     <= r) c2 += cf * __expf(iv * (float)(di2 + d2 * d2));
            int d3 = dj + 3;
            if (d3     >= -r && d3     <= r) c3 += cf * __expf(iv * (float)(di2 + d3 * d3));
        }
    }

    const int idx = row * (WW / 4) + t;
    float4 f  = field[idx];
    float4 sg = signal[idx];

    float a0 = is / (1.0f + expf(-(gr + c0)));
    float a1 = is / (1.0f + expf(-(gr + c1)));
    float a2 = is / (1.0f + expf(-(gr + c2)));
    float a3 = is / (1.0f + expf(-(gr + c3)));

    float4 u;
    u.x = f.x + (sg.x - f.x) * a0;
    u.y = f.y + (sg.y - f.y) * a1;
    u.z = f.z + (sg.z - f.z) * a2;
    u.w = f.w + (sg.w - f.w) * a3;
    out[idx] = u;

    // per-thread partial (float is plenty: 4 terms), wave-reduce in float
    float sf = f.x * f.x + f.y * f.y + f.z * f.z + f.w * f.w;
    float su = u.x * u.x + u.y * u.y + u.z * u.z + u.w * u.w;
#pragma unroll
    for (int off = 32; off > 0; off >>= 1) {
        sf += __shfl_down(sf, off, 64);
        su += __shfl_down(su, off, 64);
    }
    int wave = t >> 6;
    if ((t & 63) == 0) {
        s_part[0][wave] = sf;
        s_part[1][wave] = su;
    }
    __syncthreads();
    if (t == 0) {
        pf[blockIdx.x] = (double)s_part[0][0] + (double)s_part[0][1]
                       + (double)s_part[0][2] + (double)s_part[0][3];
        pu[blockIdx.x] = (double)s_part[1][0] + (double)s_part[1][1]
                       + (double)s_part[1][2] + (double)s_part[1][3];
    }
}

// Kernel 2: single block reduces 1024 partial pairs, computes scale.
__global__ __launch_bounds__(256) void frp_reduce(
    const double* __restrict__ pf,
    const double* __restrict__ pu,
    float* __restrict__ scale)
{
    __shared__ double sp[2][4];
    int t = threadIdx.x;
    double sf = 0.0, su = 0.0;
#pragma unroll
    for (int i = 0; i < NBLK / 256; ++i) {
        sf += pf[t + 256 * i];
        su += pu[t + 256 * i];
    }
#pragma unroll
    for (int off = 32; off > 0; off >>= 1) {
        sf += __shfl_down(sf, off, 64);
        su += __shfl_down(su, off, 64);
    }
    int wave = t >> 6;
    if ((t & 63) == 0) { sp[0][wave] = sf; sp[1][wave] = su; }
    __syncthreads();
    if (t == 0) {
        double tf = sp[0][0] + sp[0][1] + sp[0][2] + sp[0][3];
        double tu = sp[1][0] + sp[1][1] + sp[1][2] + sp[1][3];
        *scale = (tu > 0.0) ? (float)sqrt(tf / tu) : 1.0f;
    }
}

// Kernel 3: scale out in place.
__global__ __launch_bounds__(256) void frp_scale(
    float4* __restrict__ out, const float* __restrict__ scale)
{
    float s = *scale;
    int p = blockIdx.x * 256 + threadIdx.x;   // 262144 float4s
    float4 v = out[p];
    v.x *= s; v.y *= s; v.z *= s; v.w *= s;
    out[p] = v;
}

extern "C" void kernel_launch(void* const* d_in, const int* in_sizes, int n_in,
                              void* d_out, int out_size, void* d_ws, size_t ws_size,
                              hipStream_t stream) {
    const float* field  = (const float*)d_in[0];
    const float* signal = (const float*)d_in[1];
    const int*   apos   = (const int*)d_in[2];
    const float* astr   = (const float*)d_in[3];
    const float* p_is   = (const float*)d_in[4];
    const float* p_gr   = (const float*)d_in[5];
    const float* p_lr   = (const float*)d_in[6];

    double* pf    = (double*)d_ws;
    double* pu    = pf + NBLK;
    float*  scale = (float*)(pu + NBLK);

    frp_fused<<<NBLK, 256, 0, stream>>>(
        (const float4*)field, (const float4*)signal, apos, astr,
        p_is, p_gr, p_lr, (float4*)d_out, pf, pu);

    frp_reduce<<<1, 256, 0, stream>>>(pf, pu, scale);

    frp_scale<<<(HH * WW) / (256 * 4), 256, 0, stream>>>(
        (float4*)d_out, scale);
}

// Round 3
// 13.725 us; speedup vs baseline: 8.6052x; 1.2772x over previous
//
#include <hip/hip_runtime.h>

#define HH 1024
#define WW 1024
#define NA 64
#define NBLK 1024   // kernel-1 blocks: one row per block

// ws layout: pf[NBLK] doubles, pu[NBLK] doubles.

// Kernel 1: influence map + blend, one row per block, 4 px/thread.
// Wave 0 compacts the row-active attractors (avg ~1.1 of 64) into LDS.
__global__ __launch_bounds__(256) void frp_fused(
    const float4* __restrict__ field,
    const float4* __restrict__ signal,
    const int*   __restrict__ apos,       // [NA][2]
    const float* __restrict__ astr,       // [NA]
    const float* __restrict__ p_is,
    const float* __restrict__ p_gr,
    const float* __restrict__ p_lr,
    float4* __restrict__ out,
    double* __restrict__ pf,
    double* __restrict__ pu)
{
    __shared__ int   s_pj[NA];
    __shared__ int   s_rad[NA];
    __shared__ int   s_di2[NA];
    __shared__ float s_coef[NA];
    __shared__ float s_inv[NA];
    __shared__ int   s_nact;
    __shared__ float s_part[2][4];

    const float lr = *p_lr;
    const float gr = *p_gr;
    const float is = *p_is;

    const int row = blockIdx.x;
    const int t   = threadIdx.x;

    if (t < NA) {                         // exactly wave 0
        float s  = astr[t];
        int   pi = apos[2 * t + 0];
        int   pj = apos[2 * t + 1];
        int   r  = (int)floorf(5.0f * s);
        int   di = row - pi;
        bool active = (di >= -r && di <= r);
        unsigned long long mask = __ballot(active);
        int pos = __popcll(mask & ((1ull << t) - 1ull));
        if (active) {
            s_pj[pos]   = pj;
            s_rad[pos]  = r;
            s_di2[pos]  = di * di;
            s_coef[pos] = lr * s;
            s_inv[pos]  = -0.125f / (s * s);   // = -0.5 / (4 s^2)
        }
        if (t == 0) s_nact = __popcll(mask);
    }
    __syncthreads();

    const int col0 = t << 2;              // 4 consecutive columns per thread
    const int n    = s_nact;

    float c0 = 0.f, c1 = 0.f, c2 = 0.f, c3 = 0.f;
    for (int k = 0; k < n; ++k) {         // ~1 iteration on average
        int   pj  = s_pj[k];              // broadcast LDS reads (conflict-free)
        int   r   = s_rad[k];
        int   di2 = s_di2[k];
        float cf  = s_coef[k];
        float iv  = s_inv[k];
        int dj = col0 - pj;
        if (dj >= -r && dj <= r) c0 += cf * __expf(iv * (float)(di2 + dj * dj));
        int d1 = dj + 1;
        if (d1 >= -r && d1 <= r) c1 += cf * __expf(iv * (float)(di2 + d1 * d1));
        int d2 = dj + 2;
        if (d2 >= -r && d2 <= r) c2 += cf * __expf(iv * (float)(di2 + d2 * d2));
        int d3 = dj + 3;
        if (d3 >= -r && d3 <= r) c3 += cf * __expf(iv * (float)(di2 + d3 * d3));
    }

    const int idx = row * (WW / 4) + t;
    float4 f  = field[idx];
    float4 sg = signal[idx];

    float a0 = is / (1.0f + expf(-(gr + c0)));
    float a1 = is / (1.0f + expf(-(gr + c1)));
    float a2 = is / (1.0f + expf(-(gr + c2)));
    float a3 = is / (1.0f + expf(-(gr + c3)));

    float4 u;
    u.x = f.x + (sg.x - f.x) * a0;
    u.y = f.y + (sg.y - f.y) * a1;
    u.z = f.z + (sg.z - f.z) * a2;
    u.w = f.w + (sg.w - f.w) * a3;
    out[idx] = u;

    float sf = f.x * f.x + f.y * f.y + f.z * f.z + f.w * f.w;
    float su = u.x * u.x + u.y * u.y + u.z * u.z + u.w * u.w;
#pragma unroll
    for (int off = 32; off > 0; off >>= 1) {
        sf += __shfl_down(sf, off, 64);
        su += __shfl_down(su, off, 64);
    }
    const int wave = t >> 6;
    if ((t & 63) == 0) {
        s_part[0][wave] = sf;
        s_part[1][wave] = su;
    }
    __syncthreads();
    if (t == 0) {
        pf[blockIdx.x] = (double)s_part[0][0] + (double)s_part[0][1]
                       + (double)s_part[0][2] + (double)s_part[0][3];
        pu[blockIdx.x] = (double)s_part[1][0] + (double)s_part[1][1]
                       + (double)s_part[1][2] + (double)s_part[1][3];
    }
}

// Kernel 2: every block redundantly reduces the 1024 partial pairs
// (16 KB, L2-hit), computes scale, and scales its slice of out.
__global__ __launch_bounds__(256) void frp_scale(
    float4* __restrict__ out,
    const double* __restrict__ pf,
    const double* __restrict__ pu)
{
    __shared__ double sp[2][4];
    __shared__ float  s_scale;
    const int t = threadIdx.x;

    double sf = 0.0, su = 0.0;
#pragma unroll
    for (int i = 0; i < NBLK / 256; ++i) {
        sf += pf[t + 256 * i];
        su += pu[t + 256 * i];
    }
#pragma unroll
    for (int off = 32; off > 0; off >>= 1) {
        sf += __shfl_down(sf, off, 64);
        su += __shfl_down(su, off, 64);
    }
    const int wave = t >> 6;
    if ((t & 63) == 0) { sp[0][wave] = sf; sp[1][wave] = su; }
    __syncthreads();
    if (t == 0) {
        double tf = sp[0][0] + sp[0][1] + sp[0][2] + sp[0][3];
        double tu = sp[1][0] + sp[1][1] + sp[1][2] + sp[1][3];
        s_scale = (tu > 0.0) ? (float)sqrt(tf / tu) : 1.0f;
    }
    __syncthreads();

    const float s = s_scale;
    const int idx = blockIdx.x * 256 + t;   // 1024 blocks * 256 = 262144 float4
    float4 v = out[idx];
    v.x *= s; v.y *= s; v.z *= s; v.w *= s;
    out[idx] = v;
}

extern "C" void kernel_launch(void* const* d_in, const int* in_sizes, int n_in,
                              void* d_out, int out_size, void* d_ws, size_t ws_size,
                              hipStream_t stream) {
    const float* field  = (const float*)d_in[0];
    const float* signal = (const float*)d_in[1];
    const int*   apos   = (const int*)d_in[2];
    const float* astr   = (const float*)d_in[3];
    const float* p_is   = (const float*)d_in[4];
    const float* p_gr   = (const float*)d_in[5];
    const float* p_lr   = (const float*)d_in[6];

    double* pf = (double*)d_ws;
    double* pu = pf + NBLK;

    frp_fused<<<NBLK, 256, 0, stream>>>(
        (const float4*)field, (const float4*)signal, apos, astr,
        p_is, p_gr, p_lr, (float4*)d_out, pf, pu);

    frp_scale<<<(HH * WW) / (256 * 4), 256, 0, stream>>>(
        (float4*)d_out, pf, pu);
}